// Round 7
// baseline (314.663 us; speedup 1.0000x reference)
//
#include <hip/hip_runtime.h>
#include <hip/hip_bf16.h>

static constexpr int M_TOT = 8192;   // 4 * 2048
static constexpr int N_TOT = 4096;   // OUT_F
static constexpr int K_TOT = 4096;   // IN_F

static constexpr int BM = 128, BN = 256, BK = 32;
static constexpr int NT = K_TOT / BK;            // 128 K-tiles
static constexpr int GTHREADS = 512;             // 8 waves (2 M x 4 N of 64x64)
static constexpr int BUF_BYTES = 24576;          // A 8K + B 16K
static constexpr int LDS_BYTES = 3 * BUF_BYTES;  // ring-3 = 72 KiB -> 2 blocks/CU

typedef __bf16 bf16x8 __attribute__((ext_vector_type(8)));
typedef float f32x4 __attribute__((ext_vector_type(4)));
typedef unsigned short u16x8 __attribute__((ext_vector_type(8)));

__device__ __forceinline__ unsigned short f2bf(float f) {
  return __builtin_bit_cast(unsigned short, (__bf16)f);
}

// FP4 E2M1 decode: mag 0..7 -> 0,0.5,1,1.5,2,3,4,6 ; bit 3 = sign
__device__ __forceinline__ float fp4_decode(int idx) {
  unsigned u = (unsigned)idx & 15u;
  unsigned sgn = (u >> 3) << 31;
  unsigned mag = u & 7u;
  unsigned e = mag >> 1, m = mag & 1u;
  unsigned bits = (e == 0u) ? (m ? 0x3F000000u : 0u)
                            : (((126u + e) << 23) | (m << 22));
  return __uint_as_float(bits | sgn);
}

__device__ __forceinline__ void glds16(const void* g, void* l) {
  __builtin_amdgcn_global_load_lds(
      (__attribute__((address_space(1))) void*)g,
      (__attribute__((address_space(3))) void*)l, 16, 0, 0);
}

// ---- prepass: weights int32 idx + scales -> bf16 W [N][K] -------------------
__global__ __launch_bounds__(256) void dequant_w_kernel(
    const int* __restrict__ idx, const float* __restrict__ scales,
    unsigned short* __restrict__ W) {
  const int t = blockIdx.x * 256 + threadIdx.x;  // 4 indices per thread
  const int4 v = reinterpret_cast<const int4*>(idx)[t];
  const float s = scales[t >> 2];
  ushort4 o;
  o.x = f2bf(fp4_decode(v.x) * s);
  o.y = f2bf(fp4_decode(v.y) * s);
  o.z = f2bf(fp4_decode(v.z) * s);
  o.w = f2bf(fp4_decode(v.w) * s);
  reinterpret_cast<ushort4*>(W)[t] = o;
}

// ---- prepass: x fp32 -> bf16 A [M][K] ---------------------------------------
__global__ __launch_bounds__(256) void convert_x_kernel(
    const float* __restrict__ x, unsigned short* __restrict__ A) {
  const int t = blockIdx.x * 256 + threadIdx.x;  // 8 floats per thread
  const float4* xp = reinterpret_cast<const float4*>(x);
  const float4 a = xp[2 * t], b = xp[2 * t + 1];
  u16x8 o;
  o[0] = f2bf(a.x); o[1] = f2bf(a.y); o[2] = f2bf(a.z); o[3] = f2bf(a.w);
  o[4] = f2bf(b.x); o[5] = f2bf(b.y); o[6] = f2bf(b.z); o[7] = f2bf(b.w);
  reinterpret_cast<u16x8*>(A)[t] = o;
}

// ---- GEMM: 128x256, BK=32, ring-3 LDS, 2 blocks/CU (4 waves/SIMD TLP) -------
// LDS per buf: A[128][32] @ +0, B[256][32] @ +8192. 64 B rows, stored chunk =
// global chunk ^ ((row>>1)&3)  (R3's measured-zero-conflict involution).
// Schedule/tile t: {ds_read 8 frags(buf t%3) ; stage tile t+2 -> buf (t+2)%3 ;
// MFMA 16 ; vmcnt(3) [= tile t+1 landed] ; barrier}. One barrier per tile;
// cross-block TLP hides the stalls.
__global__ __launch_bounds__(GTHREADS, 4) void gemm128x256(
    const unsigned short* __restrict__ A, const unsigned short* __restrict__ B,
    const float* __restrict__ bias, float* __restrict__ out) {
  extern __shared__ char smem[];

  const int t = threadIdx.x;
  const int lane = t & 63, wid = t >> 6;
  const int wrm = wid >> 2;         // 0..1 (M half: 64 rows)
  const int wcn = wid & 3;          // 0..3 (N quarter: 64 cols)
  const int l15 = lane & 15;
  const int kc = lane >> 4;         // 0..3

  // XCD swizzle: 1024 blocks = 8 xcd x 8 bm_hi x 16 bn ; bmi = xcd*8 + bm_lo
  const int bid = blockIdx.x;
  const int bmi = (bid & 7) * 8 + ((bid >> 3) & 7);  // 0..63
  const int bni = bid >> 6;                          // 0..15
  const int bm0 = bmi * BM, bn0 = bni * BN;

  // staging: thread t -> 16B chunk t (row t>>2), source k-chunk pre-swizzled
  const int row_s = t >> 2;                   // 0..127
  const int kcd = (t & 3) ^ ((t >> 3) & 3);
  const unsigned short* gA = A + (size_t)(bm0 + row_s) * K_TOT + kcd * 8;
  const unsigned short* gB = B + (size_t)(bn0 + row_s) * K_TOT + kcd * 8;
  const unsigned short* gB1 = gB + (size_t)128 * K_TOT;   // B rows 128-255
  const int tid16 = t * 16;

  // ds_read: same involution (frag rows = mult-of-16 + l15)
  const int swz = (kc ^ ((l15 >> 1) & 3)) * 16;
  const int base_a = (wrm * 64 + l15) * 64 + swz;
  const int base_b = 8192 + (wcn * 64 + l15) * 64 + swz;

  f32x4 acc[4][4];
#pragma unroll
  for (int i = 0; i < 4; ++i)
#pragma unroll
    for (int j = 0; j < 4; ++j) acc[i][j] = f32x4{0.f, 0.f, 0.f, 0.f};

  bf16x8 af[4], bf[4];

#define STG(kt, soff) do {                                   \
    const int ko_ = (kt) * BK;                               \
    glds16(gA + ko_, smem + (soff) + tid16);                 \
    glds16(gB + ko_, smem + (soff) + 8192 + tid16);          \
    glds16(gB1 + ko_, smem + (soff) + 16384 + tid16);        \
  } while (0)

#define RD(cboff) do {                                       \
    const char* pa_ = smem + (cboff) + base_a;               \
    const char* pb_ = smem + (cboff) + base_b;               \
    af[0] = *(const bf16x8*)(pa_);                           \
    af[1] = *(const bf16x8*)(pa_ + 1024);                    \
    af[2] = *(const bf16x8*)(pa_ + 2048);                    \
    af[3] = *(const bf16x8*)(pa_ + 3072);                    \
    bf[0] = *(const bf16x8*)(pb_);                           \
    bf[1] = *(const bf16x8*)(pb_ + 1024);                    \
    bf[2] = *(const bf16x8*)(pb_ + 2048);                    \
    bf[3] = *(const bf16x8*)(pb_ + 3072);                    \
  } while (0)

#define MF16() do {                                          \
    __builtin_amdgcn_s_setprio(1);                           \
    _Pragma("unroll")                                        \
    for (int m_ = 0; m_ < 4; ++m_)                           \
      _Pragma("unroll")                                      \
      for (int n_ = 0; n_ < 4; ++n_)                         \
        acc[m_][n_] = __builtin_amdgcn_mfma_f32_16x16x32_bf16( \
            af[m_], bf[n_], acc[m_][n_], 0, 0, 0);           \
    __builtin_amdgcn_s_setprio(0);                           \
  } while (0)

#define VM(n) asm volatile("s_waitcnt vmcnt(" #n ")" ::: "memory")
#define BAR __builtin_amdgcn_s_barrier()

  // Phase: reads(cb) ; stage t+2 -> sb ; MFMA ; vmcnt(3) ; barrier.
#define PH(tt, cboff, sboff) do {  \
    RD(cboff);                     \
    STG((tt) + 2, sboff);          \
    MF16();                        \
    VM(3); BAR;                    \
  } while (0)

  // ---- prologue: stage tiles 0,1 ; gate tile 0
  STG(0, 0);
  asm volatile("" ::: "memory");
  STG(1, BUF_BYTES);
  VM(3);  // tile 0 landed (own); BAR makes it global
  BAR;

  // ---- main loop: tiles 0..125 (3-tile unroll, static ring offsets)
#pragma unroll 1
  for (int i = 0; i < 42; ++i) {
    const int T = 3 * i;
    PH(T + 0, 0, 2 * BUF_BYTES);
    PH(T + 1, BUF_BYTES, 0);
    PH(T + 2, 2 * BUF_BYTES, BUF_BYTES);
  }

  // ---- tail: tile 126 (buf0; drain tile 127's loads), tile 127 (buf1)
  RD(0);
  MF16();
  VM(0); BAR;
  RD(BUF_BYTES);
  MF16();

  // ---- epilogue: C/D layout col = lane&15, row = (lane>>4)*4 + q
  const int orow0 = bm0 + wrm * 64 + (lane >> 4) * 4;
  const int ocol0 = bn0 + wcn * 64 + l15;
  float bj[4];
#pragma unroll
  for (int n = 0; n < 4; ++n) bj[n] = bias[ocol0 + n * 16];
#pragma unroll
  for (int mi = 0; mi < 4; ++mi)
#pragma unroll
    for (int n = 0; n < 4; ++n)
#pragma unroll
      for (int q = 0; q < 4; ++q)
        out[(size_t)(orow0 + mi * 16 + q) * N_TOT + ocol0 + n * 16] =
            acc[mi][n][q] + bj[n];
}

extern "C" void kernel_launch(void* const* d_in, const int* in_sizes, int n_in,
                              void* d_out, int out_size, void* d_ws, size_t ws_size,
                              hipStream_t stream) {
  const float* x = (const float*)d_in[0];
  const int* widx = (const int*)d_in[1];
  const float* wsc = (const float*)d_in[2];
  const float* bias = (const float*)d_in[3];
  float* out = (float*)d_out;

  unsigned short* Abf = (unsigned short*)d_ws;                       // 64 MiB
  unsigned short* Wbf = (unsigned short*)((char*)d_ws + (size_t)M_TOT * K_TOT * 2);  // 32 MiB

  convert_x_kernel<<<dim3((M_TOT * (size_t)K_TOT / 8) / 256), dim3(256), 0, stream>>>(x, Abf);
  dequant_w_kernel<<<dim3((N_TOT * (size_t)K_TOT / 4) / 256), dim3(256), 0, stream>>>(widx, wsc, Wbf);

  (void)hipFuncSetAttribute((const void*)gemm128x256,
                            hipFuncAttributeMaxDynamicSharedMemorySize, LDS_BYTES);
  gemm128x256<<<dim3((M_TOT / BM) * (N_TOT / BN)), dim3(GTHREADS), LDS_BYTES, stream>>>(
      Abf, Wbf, bias, out);
}

// Round 8
// 283.726 us; speedup vs baseline: 1.1090x; 1.1090x over previous
//
#include <hip/hip_runtime.h>
#include <hip/hip_bf16.h>

static constexpr int M_TOT = 8192;   // 4 * 2048
static constexpr int N_TOT = 4096;   // OUT_F
static constexpr int K_TOT = 4096;   // IN_F

static constexpr int BM = 256, BN = 256, BK = 32;
static constexpr int NT = K_TOT / BK;        // 128 K-tiles
static constexpr int GTHREADS = 512;         // 8 waves (2 M x 4 N)
static constexpr int BUF_BYTES = 32768;      // A 16K + B 16K per K-tile buffer
static constexpr int LDS_BYTES = 4 * BUF_BYTES;  // ring-4 = 128 KiB

typedef __bf16 bf16x8 __attribute__((ext_vector_type(8)));
typedef float f32x4 __attribute__((ext_vector_type(4)));
typedef unsigned short u16x8 __attribute__((ext_vector_type(8)));

__device__ __forceinline__ unsigned short f2bf(float f) {
  return __builtin_bit_cast(unsigned short, (__bf16)f);
}

// FP4 E2M1 decode: mag 0..7 -> 0,0.5,1,1.5,2,3,4,6 ; bit 3 = sign
__device__ __forceinline__ float fp4_decode(int idx) {
  unsigned u = (unsigned)idx & 15u;
  unsigned sgn = (u >> 3) << 31;
  unsigned mag = u & 7u;
  unsigned e = mag >> 1, m = mag & 1u;
  unsigned bits = (e == 0u) ? (m ? 0x3F000000u : 0u)
                            : (((126u + e) << 23) | (m << 22));
  return __uint_as_float(bits | sgn);
}

__device__ __forceinline__ void glds16(const void* g, void* l) {
  __builtin_amdgcn_global_load_lds(
      (__attribute__((address_space(1))) void*)g,
      (__attribute__((address_space(3))) void*)l, 16, 0, 0);
}

// ---- prepass: weights int32 idx + scales -> bf16 W [N][K] -------------------
__global__ __launch_bounds__(256) void dequant_w_kernel(
    const int* __restrict__ idx, const float* __restrict__ scales,
    unsigned short* __restrict__ W) {
  const int t = blockIdx.x * 256 + threadIdx.x;  // 4 indices per thread
  const int4 v = reinterpret_cast<const int4*>(idx)[t];
  const float s = scales[t >> 2];
  ushort4 o;
  o.x = f2bf(fp4_decode(v.x) * s);
  o.y = f2bf(fp4_decode(v.y) * s);
  o.z = f2bf(fp4_decode(v.z) * s);
  o.w = f2bf(fp4_decode(v.w) * s);
  reinterpret_cast<ushort4*>(W)[t] = o;
}

// ---- prepass: x fp32 -> bf16 A [M][K] ---------------------------------------
__global__ __launch_bounds__(256) void convert_x_kernel(
    const float* __restrict__ x, unsigned short* __restrict__ A) {
  const int t = blockIdx.x * 256 + threadIdx.x;  // 8 floats per thread
  const float4* xp = reinterpret_cast<const float4*>(x);
  const float4 a = xp[2 * t], b = xp[2 * t + 1];
  u16x8 o;
  o[0] = f2bf(a.x); o[1] = f2bf(a.y); o[2] = f2bf(a.z); o[3] = f2bf(a.w);
  o[4] = f2bf(b.x); o[5] = f2bf(b.y); o[6] = f2bf(b.z); o[7] = f2bf(b.w);
  reinterpret_cast<u16x8*>(A)[t] = o;
}

// ---- GEMM: 256x256, BK=32, ring-4 LDS, merged 1-barrier phase, vmcnt(8) -----
// Phase tt: {STG tile tt+3 (4 glds) ; RD 12 frags of buf tt&3 ; 32 MFMA ;
// VM(8) ; BAR}. Gate: newest 8 glds (tiles tt+2,tt+3) may be outstanding =>
// tile tt+1 landed globally after BAR. WAR: buf (tt+3)&3's last ds_reads were
// consumed by phase tt-1's MFMAs (compiler lgkmcnt) before BAR(tt-1).
__global__ __launch_bounds__(GTHREADS, 1) void gemm256(
    const unsigned short* __restrict__ A, const unsigned short* __restrict__ B,
    const float* __restrict__ bias, float* __restrict__ out) {
  extern __shared__ char smem[];

  const int t = threadIdx.x;
  const int lane = t & 63, wid = t >> 6;
  const int wr = wid >> 2;          // 0..1 (M half, 128 rows)
  const int wc = wid & 3;           // 0..3 (N quarter, 64 cols)
  const int ln = lane & 15;
  const int kc = lane >> 4;         // 0..3 k-chunk of 8 bf16

  // T1: XCD swizzle (512 blocks, 8 XCDs)
  const int bid = blockIdx.x;
  const int bmi = (bid & 7) * 4 + ((bid >> 3) & 3);  // 0..31
  const int bni = bid >> 5;                          // 0..15
  const int bm0 = bmi * BM, bn0 = bni * BN;

  // staging: linear LDS dest; source k-chunk pre-swizzled with the involution
  // c' = c ^ ((row>>1)&3)  (measured-zero-conflict layout, R3/R6)
  const int row_s = t >> 2;                   // 0..127
  const int kcd = (t & 3) ^ ((t >> 3) & 3);   // pre-swizzled global k-chunk
  const unsigned short* gA = A + (size_t)(bm0 + row_s) * K_TOT + kcd * 8;
  const unsigned short* gB = B + (size_t)(bn0 + row_s) * K_TOT + kcd * 8;
  char* ldsA = smem + t * 16;
  char* ldsB = smem + 16384 + t * 16;

  // ds_read side: same involution ((row>>1)&3 == (ln>>1)&3, rows mult of 16)
  const int swz = (kc ^ ((ln >> 1) & 3)) * 16;
  const int base_a = (wr * 128 + ln) * 64 + swz;
  const int base_b = 16384 + (wc * 64 + ln) * 64 + swz;

  f32x4 acc[8][4];
#pragma unroll
  for (int i = 0; i < 8; ++i)
#pragma unroll
    for (int j = 0; j < 4; ++j) acc[i][j] = f32x4{0.f, 0.f, 0.f, 0.f};

  bf16x8 af[8], bf[4];

#define STAGE_A(kt, bufi) do {                                          \
    const unsigned short* p_ = gA + (size_t)(kt) * BK;                  \
    glds16(p_, ldsA + (bufi) * BUF_BYTES);                              \
    glds16(p_ + (size_t)128 * K_TOT, ldsA + (bufi) * BUF_BYTES + 8192); \
  } while (0)
#define STAGE_B(kt, bufi) do {                                          \
    const unsigned short* p_ = gB + (size_t)(kt) * BK;                  \
    glds16(p_, ldsB + (bufi) * BUF_BYTES);                              \
    glds16(p_ + (size_t)128 * K_TOT, ldsB + (bufi) * BUF_BYTES + 8192); \
  } while (0)

  // Read order: af0-3, bf0-3 first (operands of the first 16 MFMAs), af4-7
  // last — lets the compiler release the m0-3 MFMA block on a partial lgkmcnt.
#define RD_ALL(bufi) do {                                               \
    const char* pa_ = smem + (bufi) * BUF_BYTES + base_a;               \
    const char* pb_ = smem + (bufi) * BUF_BYTES + base_b;               \
    af[0] = *(const bf16x8*)(pa_);                                      \
    af[1] = *(const bf16x8*)(pa_ + 1024);                               \
    af[2] = *(const bf16x8*)(pa_ + 2048);                               \
    af[3] = *(const bf16x8*)(pa_ + 3072);                               \
    bf[0] = *(const bf16x8*)(pb_);                                      \
    bf[1] = *(const bf16x8*)(pb_ + 1024);                               \
    bf[2] = *(const bf16x8*)(pb_ + 2048);                               \
    bf[3] = *(const bf16x8*)(pb_ + 3072);                               \
    af[4] = *(const bf16x8*)(pa_ + 4096);                               \
    af[5] = *(const bf16x8*)(pa_ + 5120);                               \
    af[6] = *(const bf16x8*)(pa_ + 6144);                               \
    af[7] = *(const bf16x8*)(pa_ + 7168);                               \
  } while (0)

#define MF32() do {                                                     \
    __builtin_amdgcn_s_setprio(1);                                      \
    _Pragma("unroll")                                                   \
    for (int m_ = 0; m_ < 8; ++m_)                                      \
      _Pragma("unroll")                                                 \
      for (int n_ = 0; n_ < 4; ++n_)                                    \
        acc[m_][n_] = __builtin_amdgcn_mfma_f32_16x16x32_bf16(          \
            af[m_], bf[n_], acc[m_][n_], 0, 0, 0);                      \
    __builtin_amdgcn_s_setprio(0);                                      \
  } while (0)

#define VM(n) asm volatile("s_waitcnt vmcnt(" #n ")" ::: "memory")
#define BAR __builtin_amdgcn_s_barrier()

  // Merged phase: one barrier + one counted gate per K-tile.
#define PH(tt, cb, sb) do { \
    STAGE_A((tt) + 3, sb);  \
    STAGE_B((tt) + 3, sb);  \
    RD_ALL(cb);             \
    MF32();                 \
    VM(8); BAR;             \
  } while (0)

  // ---- prologue: stage tiles 0,1,2 (order pinned for vmcnt accounting)
  STAGE_A(0, 0); STAGE_B(0, 0);
  asm volatile("" ::: "memory");
  STAGE_A(1, 1); STAGE_B(1, 1);
  asm volatile("" ::: "memory");
  STAGE_A(2, 2); STAGE_B(2, 2);
  VM(8);  // tile 0 landed (own); barrier makes it global
  BAR;

  // ---- main loop: tiles 0..123, staging 3..126 (4-tile unroll, static bufs)
#pragma unroll 1
  for (int tt = 0; tt < NT - 4; tt += 4) {
    PH(tt + 0, 0, 3);
    PH(tt + 1, 1, 0);
    PH(tt + 2, 2, 1);
    PH(tt + 3, 3, 2);
  }

  // ---- tile 124 (buf0): stages tile 127 -> buf3
  PH(124, 0, 3);
  // ---- tail: tiles 125..127, drain 8 -> 4 -> 0
  RD_ALL(1); MF32(); VM(4); BAR;   // tile 125; 126 landed after gate
  RD_ALL(2); MF32(); VM(0); BAR;   // tile 126; 127 landed
  RD_ALL(3); MF32();               // tile 127

  // ---- epilogue: C/D layout col = lane&15, row = (lane>>4)*4 + q
  const int orow0 = bm0 + wr * 128 + (lane >> 4) * 4;
  const int ocol0 = bn0 + wc * 64 + ln;
  float bj[4];
#pragma unroll
  for (int n = 0; n < 4; ++n) bj[n] = bias[ocol0 + n * 16];
#pragma unroll
  for (int mi = 0; mi < 8; ++mi)
#pragma unroll
    for (int n = 0; n < 4; ++n)
#pragma unroll
      for (int q = 0; q < 4; ++q)
        out[(size_t)(orow0 + mi * 16 + q) * N_TOT + ocol0 + n * 16] =
            acc[mi][n][q] + bj[n];
}

extern "C" void kernel_launch(void* const* d_in, const int* in_sizes, int n_in,
                              void* d_out, int out_size, void* d_ws, size_t ws_size,
                              hipStream_t stream) {
  const float* x = (const float*)d_in[0];
  const int* widx = (const int*)d_in[1];
  const float* wsc = (const float*)d_in[2];
  const float* bias = (const float*)d_in[3];
  float* out = (float*)d_out;

  unsigned short* Abf = (unsigned short*)d_ws;                       // 64 MiB
  unsigned short* Wbf = (unsigned short*)((char*)d_ws + (size_t)M_TOT * K_TOT * 2);  // 32 MiB

  convert_x_kernel<<<dim3((M_TOT * (size_t)K_TOT / 8) / 256), dim3(256), 0, stream>>>(x, Abf);
  dequant_w_kernel<<<dim3((N_TOT * (size_t)K_TOT / 4) / 256), dim3(256), 0, stream>>>(widx, wsc, Wbf);

  (void)hipFuncSetAttribute((const void*)gemm256,
                            hipFuncAttributeMaxDynamicSharedMemorySize, LDS_BYTES);
  gemm256<<<dim3((M_TOT / BM) * (N_TOT / BN)), dim3(GTHREADS), LDS_BYTES, stream>>>(
      Abf, Wbf, bias, out);
}

// Round 9
// 282.469 us; speedup vs baseline: 1.1140x; 1.0044x over previous
//
#include <hip/hip_runtime.h>
#include <hip/hip_bf16.h>

static constexpr int M_TOT = 8192;   // 4 * 2048
static constexpr int N_TOT = 4096;   // OUT_F
static constexpr int K_TOT = 4096;   // IN_F

static constexpr int BM = 256, BN = 256;
static constexpr int GTHREADS = 512;            // 8 waves (2 M x 4 N)
static constexpr int LDS_BYTES = 131072;        // 2 dbuf x (A 32K + B 32K)
static constexpr int D1 = 65536;                // dbuf1 offset

typedef __bf16 bf16x8 __attribute__((ext_vector_type(8)));
typedef float f32x4 __attribute__((ext_vector_type(4)));
typedef unsigned short u16x8 __attribute__((ext_vector_type(8)));

__device__ __forceinline__ unsigned short f2bf(float f) {
  return __builtin_bit_cast(unsigned short, (__bf16)f);
}

// FP4 E2M1 decode: mag 0..7 -> 0,0.5,1,1.5,2,3,4,6 ; bit 3 = sign
__device__ __forceinline__ float fp4_decode(int idx) {
  unsigned u = (unsigned)idx & 15u;
  unsigned sgn = (u >> 3) << 31;
  unsigned mag = u & 7u;
  unsigned e = mag >> 1, m = mag & 1u;
  unsigned bits = (e == 0u) ? (m ? 0x3F000000u : 0u)
                            : (((126u + e) << 23) | (m << 22));
  return __uint_as_float(bits | sgn);
}

__device__ __forceinline__ void glds16(const void* g, void* l) {
  __builtin_amdgcn_global_load_lds(
      (__attribute__((address_space(1))) void*)g,
      (__attribute__((address_space(3))) void*)l, 16, 0, 0);
}

// ---- merged prepass: blocks [0,16384) convert x->bf16 A; [16384,32768) W ----
__global__ __launch_bounds__(256) void prepass_kernel(
    const float* __restrict__ x, unsigned short* __restrict__ A,
    const int* __restrict__ idx, const float* __restrict__ scales,
    unsigned short* __restrict__ W) {
  const int b = blockIdx.x;
  if (b < 16384) {
    const int t = b * 256 + threadIdx.x;  // 8 floats per thread
    const float4* xp = reinterpret_cast<const float4*>(x);
    const float4 a = xp[2 * t], c = xp[2 * t + 1];
    u16x8 o;
    o[0] = f2bf(a.x); o[1] = f2bf(a.y); o[2] = f2bf(a.z); o[3] = f2bf(a.w);
    o[4] = f2bf(c.x); o[5] = f2bf(c.y); o[6] = f2bf(c.z); o[7] = f2bf(c.w);
    reinterpret_cast<u16x8*>(A)[t] = o;
  } else {
    const int t = (b - 16384) * 256 + threadIdx.x;  // 4 indices per thread
    const int4 v = reinterpret_cast<const int4*>(idx)[t];
    const float s = scales[t >> 2];
    ushort4 o;
    o.x = f2bf(fp4_decode(v.x) * s);
    o.y = f2bf(fp4_decode(v.y) * s);
    o.z = f2bf(fp4_decode(v.z) * s);
    o.w = f2bf(fp4_decode(v.w) * s);
    reinterpret_cast<ushort4*>(W)[t] = o;
  }
}

// ---- GEMM: 256x256, 8-phase schedule, m201-faithful vmcnt (gates only at
// phases 3/7, N=6), 16x16x32 MFMA, zero-conflict involution layout -----------
// LDS map per dbuf d (d0 @ 0 = even K-tiles, d1 @ 65536 = odd):
//   As0 @ +0, As1 @ +16384, Bs0 @ +32768, Bs1 @ +49152  (each 16 KB)
// Sub-tile = [256 rows][32 k] bf16, 64 B rows, stored chunk ^= (row>>1)&3.
__global__ __launch_bounds__(GTHREADS, 1) void gemm256(
    const unsigned short* __restrict__ A, const unsigned short* __restrict__ B,
    const float* __restrict__ bias, float* __restrict__ out) {
  extern __shared__ char smem[];

  const int t = threadIdx.x;
  const int lane = t & 63, wid = t >> 6;
  const int wr = wid >> 2;          // 0..1 (M half, 128 rows)
  const int wc = wid & 3;           // 0..3 (N quarter, 64 cols)
  const int l15 = lane & 15;

  // T1: XCD swizzle (512 blocks, 8 XCDs)
  const int bid = blockIdx.x;
  const int bmi = (bid & 7) * 4 + ((bid >> 3) & 3);  // 0..31
  const int bni = bid >> 5;                          // 0..15
  const int bm0 = bmi * BM, bn0 = bni * BN;

  // staging: linear LDS dest; source k-chunk pre-swizzled (c ^= (row>>1)&3)
  const int row_s = t >> 2;                   // 0..127
  const int kcd = (t & 3) ^ ((t >> 3) & 3);
  const unsigned short* pA = A + (size_t)(bm0 + row_s) * K_TOT + kcd * 8;
  const unsigned short* pB = B + (size_t)(bn0 + row_s) * K_TOT + kcd * 8;
  char* stA = smem + t * 16;           // + dbuf + s*16384 (+8192 rows 128-255)
  char* stB = smem + 32768 + t * 16;

  // ds_read side: same involution (frag rows = mult-of-16 + l15)
  const int swz = ((lane >> 4) ^ ((l15 >> 1) & 3)) * 16;
  const int base_a = (wr * 128 + l15) * 64 + swz;
  const int base_b = 32768 + (wc * 64 + l15) * 64 + swz;

  f32x4 acc[8][4];
#pragma unroll
  for (int i = 0; i < 8; ++i)
#pragma unroll
    for (int j = 0; j < 4; ++j) acc[i][j] = f32x4{0.f, 0.f, 0.f, 0.f};

  bf16x8 afQ[4], bfQ[4];

#define STG_A(T, s, doff) do {                                           \
    const unsigned short* p_ = pA + (T) * 64 + (s) * 32;                 \
    glds16(p_, stA + (doff) + (s) * 16384);                              \
    glds16(p_ + (size_t)128 * K_TOT, stA + (doff) + (s) * 16384 + 8192); \
  } while (0)
#define STG_B(T, s, doff) do {                                           \
    const unsigned short* p_ = pB + (T) * 64 + (s) * 32;                 \
    glds16(p_, stB + (doff) + (s) * 16384);                              \
    glds16(p_ + (size_t)128 * K_TOT, stB + (doff) + (s) * 16384 + 8192); \
  } while (0)

#define RD_A4(doff, s, mh) do {                                          \
    const char* p_ = smem + (doff) + (s) * 16384 + base_a + (mh) * 4096; \
    afQ[0] = *(const bf16x8*)(p_);                                       \
    afQ[1] = *(const bf16x8*)(p_ + 1024);                                \
    afQ[2] = *(const bf16x8*)(p_ + 2048);                                \
    afQ[3] = *(const bf16x8*)(p_ + 3072);                                \
  } while (0)
#define RD_B4(doff, s) do {                                              \
    const char* p_ = smem + (doff) + (s) * 16384 + base_b;               \
    bfQ[0] = *(const bf16x8*)(p_);                                       \
    bfQ[1] = *(const bf16x8*)(p_ + 1024);                                \
    bfQ[2] = *(const bf16x8*)(p_ + 2048);                                \
    bfQ[3] = *(const bf16x8*)(p_ + 3072);                                \
  } while (0)

#define MF16(mb) do {                                                    \
    __builtin_amdgcn_s_setprio(1);                                       \
    _Pragma("unroll")                                                    \
    for (int m_ = 0; m_ < 4; ++m_)                                       \
      _Pragma("unroll")                                                  \
      for (int n_ = 0; n_ < 4; ++n_)                                     \
        acc[(mb) + m_][n_] = __builtin_amdgcn_mfma_f32_16x16x32_bf16(    \
            afQ[m_], bfQ[n_], acc[(mb) + m_][n_], 0, 0, 0);              \
    __builtin_amdgcn_s_setprio(0);                                       \
  } while (0)

#define VM(n) asm volatile("s_waitcnt vmcnt(" #n ")" ::: "memory")
#define BAR __builtin_amdgcn_s_barrier()

  // ---- prologue: 7 subs in the order iter(-1) ph1..ph7 would stage them
  STG_B(0, 0, 0);      // d0.Bs0(T0)
  STG_A(0, 0, 0);      // d0.As0(T0)
  STG_B(0, 1, 0);      // d0.Bs1(T0)
  STG_A(0, 1, 0);      // d0.As1(T0)
  STG_B(1, 0, D1);     // d1.Bs0(T1)
  STG_A(1, 0, D1);     // d1.As0(T1)
  STG_B(1, 1, D1);     // d1.Bs1(T1)
  VM(6);  // newest 3 subs may fly; all of d0(T0) landed (own) -> BAR = global
  BAR;

  // ---- main loop: iters 0..30, tiles T=2i (d0) / U=2i+1 (d1)
  // Gates ONLY at ph3/ph7 ends (VM(6) = 3 subs in flight), m201-faithful.
#pragma unroll 1
  for (int i = 0; i < 31; ++i) {
    const int T = 2 * i, U = 2 * i + 1;
    // ph0: d0.s0 m0-3 ; stage d1.As1(U)
    RD_A4(0, 0, 0); RD_B4(0, 0); STG_A(U, 1, D1);
    BAR; MF16(0); BAR;
    // ph1: d0.s0 m4-7 ; stage d0.Bs0(T+2)
    RD_A4(0, 0, 1); STG_B(T + 2, 0, 0);
    BAR; MF16(4); BAR;
    // ph2: d0.s1 m0-3 ; stage d0.As0(T+2)
    RD_A4(0, 1, 0); RD_B4(0, 1); STG_A(T + 2, 0, 0);
    BAR; MF16(0); BAR;
    // ph3: d0.s1 m4-7 ; stage d0.Bs1(T+2) ; GATE
    RD_A4(0, 1, 1); STG_B(T + 2, 1, 0);
    BAR; MF16(4); VM(6); BAR;
    // ph4: d1.s0 m0-3 ; stage d0.As1(T+2)
    RD_A4(D1, 0, 0); RD_B4(D1, 0); STG_A(T + 2, 1, 0);
    BAR; MF16(0); BAR;
    // ph5: d1.s0 m4-7 ; stage d1.Bs0(U+2)
    RD_A4(D1, 0, 1); STG_B(U + 2, 0, D1);
    BAR; MF16(4); BAR;
    // ph6: d1.s1 m0-3 ; stage d1.As0(U+2)
    RD_A4(D1, 1, 0); RD_B4(D1, 1); STG_A(U + 2, 0, D1);
    BAR; MF16(0); BAR;
    // ph7: d1.s1 m4-7 ; stage d1.Bs1(U+2) ; GATE
    RD_A4(D1, 1, 1); STG_B(U + 2, 1, D1);
    BAR; MF16(4); VM(6); BAR;
  }

  // ---- final iter: tiles 62 (d0) / 63 (d1); only ph0 stages (d1.As1(63))
  RD_A4(0, 0, 0); RD_B4(0, 0); STG_A(63, 1, D1);
  BAR; MF16(0); BAR;
  RD_A4(0, 0, 1);
  BAR; MF16(4); BAR;
  RD_A4(0, 1, 0); RD_B4(0, 1);
  BAR; MF16(0); BAR;
  RD_A4(0, 1, 1);
  BAR; MF16(4); VM(0); BAR;   // drain: all of d1(63) landed
  RD_A4(D1, 0, 0); RD_B4(D1, 0);
  BAR; MF16(0); BAR;
  RD_A4(D1, 0, 1);
  BAR; MF16(4); BAR;
  RD_A4(D1, 1, 0); RD_B4(D1, 1);
  BAR; MF16(0); BAR;
  RD_A4(D1, 1, 1);
  MF16(4);

  // ---- epilogue: C/D layout col = lane&15, row = (lane>>4)*4 + q
  const int orow0 = bm0 + wr * 128 + (lane >> 4) * 4;
  const int ocol0 = bn0 + wc * 64 + l15;
  float bj[4];
#pragma unroll
  for (int n = 0; n < 4; ++n) bj[n] = bias[ocol0 + n * 16];
#pragma unroll
  for (int mi = 0; mi < 8; ++mi)
#pragma unroll
    for (int n = 0; n < 4; ++n)
#pragma unroll
      for (int q = 0; q < 4; ++q)
        out[(size_t)(orow0 + mi * 16 + q) * N_TOT + ocol0 + n * 16] =
            acc[mi][n][q] + bj[n];
}

extern "C" void kernel_launch(void* const* d_in, const int* in_sizes, int n_in,
                              void* d_out, int out_size, void* d_ws, size_t ws_size,
                              hipStream_t stream) {
  const float* x = (const float*)d_in[0];
  const int* widx = (const int*)d_in[1];
  const float* wsc = (const float*)d_in[2];
  const float* bias = (const float*)d_in[3];
  float* out = (float*)d_out;

  unsigned short* Abf = (unsigned short*)d_ws;                       // 64 MiB
  unsigned short* Wbf = (unsigned short*)((char*)d_ws + (size_t)M_TOT * K_TOT * 2);  // 32 MiB

  prepass_kernel<<<dim3(32768), dim3(256), 0, stream>>>(x, Abf, widx, wsc, Wbf);

  (void)hipFuncSetAttribute((const void*)gemm256,
                            hipFuncAttributeMaxDynamicSharedMemorySize, LDS_BYTES);
  gemm256<<<dim3((M_TOT / BM) * (N_TOT / BN)), dim3(GTHREADS), LDS_BYTES, stream>>>(
      Abf, Wbf, bias, out);
}

// Round 10
// 273.014 us; speedup vs baseline: 1.1526x; 1.0346x over previous
//
#include <hip/hip_runtime.h>
#include <hip/hip_bf16.h>

static constexpr int M_TOT = 8192;   // 4 * 2048
static constexpr int N_TOT = 4096;   // OUT_F
static constexpr int K_TOT = 4096;   // IN_F

static constexpr int BM = 256, BN = 256, BK = 32;
static constexpr int NT = K_TOT / BK;        // 128 K-tiles
static constexpr int GTHREADS = 512;         // 8 waves (2 M x 4 N)
static constexpr int BUF_BYTES = 32768;      // A 16K + B 16K per K-tile buffer
static constexpr int LDS_BYTES = 4 * BUF_BYTES;  // ring-4 = 128 KiB

typedef __bf16 bf16x8 __attribute__((ext_vector_type(8)));
typedef float f32x4 __attribute__((ext_vector_type(4)));
typedef unsigned short u16x8 __attribute__((ext_vector_type(8)));

__device__ __forceinline__ unsigned short f2bf(float f) {
  return __builtin_bit_cast(unsigned short, (__bf16)f);
}

// FP4 E2M1 decode: mag 0..7 -> 0,0.5,1,1.5,2,3,4,6 ; bit 3 = sign
__device__ __forceinline__ float fp4_decode(int idx) {
  unsigned u = (unsigned)idx & 15u;
  unsigned sgn = (u >> 3) << 31;
  unsigned mag = u & 7u;
  unsigned e = mag >> 1, m = mag & 1u;
  unsigned bits = (e == 0u) ? (m ? 0x3F000000u : 0u)
                            : (((126u + e) << 23) | (m << 22));
  return __uint_as_float(bits | sgn);
}

__device__ __forceinline__ void glds16(const void* g, void* l) {
  __builtin_amdgcn_global_load_lds(
      (__attribute__((address_space(1))) void*)g,
      (__attribute__((address_space(3))) void*)l, 16, 0, 0);
}

// ---- merged prepass: blocks [0,16384) convert x->bf16 A; [16384,32768) W ----
__global__ __launch_bounds__(256) void prepass_kernel(
    const float* __restrict__ x, unsigned short* __restrict__ A,
    const int* __restrict__ idx, const float* __restrict__ scales,
    unsigned short* __restrict__ W) {
  const int b = blockIdx.x;
  if (b < 16384) {
    const int t = b * 256 + threadIdx.x;  // 8 floats per thread
    const float4* xp = reinterpret_cast<const float4*>(x);
    const float4 a = xp[2 * t], c = xp[2 * t + 1];
    u16x8 o;
    o[0] = f2bf(a.x); o[1] = f2bf(a.y); o[2] = f2bf(a.z); o[3] = f2bf(a.w);
    o[4] = f2bf(c.x); o[5] = f2bf(c.y); o[6] = f2bf(c.z); o[7] = f2bf(c.w);
    reinterpret_cast<u16x8*>(A)[t] = o;
  } else {
    const int t = (b - 16384) * 256 + threadIdx.x;  // 4 indices per thread
    const int4 v = reinterpret_cast<const int4*>(idx)[t];
    const float s = scales[t >> 2];
    ushort4 o;
    o.x = f2bf(fp4_decode(v.x) * s);
    o.y = f2bf(fp4_decode(v.y) * s);
    o.z = f2bf(fp4_decode(v.z) * s);
    o.w = f2bf(fp4_decode(v.w) * s);
    reinterpret_cast<ushort4*>(W)[t] = o;
  }
}

// ---- GEMM (R3 champion, verbatim): 256x256, BK=32, ring-4 LDS, reg-dbuf
// frags, counted vmcnt. Measured: 226.8 us, MfmaUtil 57.6%, 0 conflicts. -----
__global__ __launch_bounds__(GTHREADS, 1) void gemm256(
    const unsigned short* __restrict__ A, const unsigned short* __restrict__ B,
    const float* __restrict__ bias, float* __restrict__ out) {
  extern __shared__ char smem[];

  const int t = threadIdx.x;
  const int lane = t & 63, wid = t >> 6;
  const int wr = wid >> 2;          // 0..1 (M half)
  const int wc = wid & 3;           // 0..3 (N quarter)
  const int ln = lane & 15;
  const int kc = lane >> 4;         // 0..3 k-chunk of 8 bf16

  // T1: XCD swizzle (512 blocks, 8 XCDs)
  const int bid = blockIdx.x;
  const int bmi = (bid & 7) * 4 + ((bid >> 3) & 3);  // 0..31
  const int bni = bid >> 5;                          // 0..15
  const int bm0 = bmi * BM, bn0 = bni * BN;

  // staging: thread t writes 16B chunk at linear LDS pos; source k-chunk
  // pre-swizzled (involution c' = c ^ ((row>>1)&3), rows are 64B)
  const int row_s = t >> 2;                   // 0..127
  const int kcd = (t & 3) ^ ((t >> 3) & 3);   // pre-swizzled global k-chunk
  const unsigned short* gA = A + (size_t)(bm0 + row_s) * K_TOT + kcd * 8;
  const unsigned short* gB = B + (size_t)(bn0 + row_s) * K_TOT + kcd * 8;
  char* ldsA = smem + t * 16;
  char* ldsB = smem + 16384 + t * 16;

  // ds_read side: same involution ((row>>1)&3 == (ln>>1)&3 since frag rows
  // differ by multiples of 16)
  const int swz = (kc ^ ((ln >> 1) & 3)) * 16;
  const int base_a = (wr * 128 + ln) * 64 + swz;
  const int base_b = 16384 + (wc * 64 + ln) * 64 + swz;

  f32x4 acc[8][4];
#pragma unroll
  for (int i = 0; i < 8; ++i)
#pragma unroll
    for (int j = 0; j < 4; ++j) acc[i][j] = f32x4{0.f, 0.f, 0.f, 0.f};

  bf16x8 afA[4], afB[4], bfE[4], bfO[4];

#define STAGE_A(kt, bufi) do {                                          \
    const unsigned short* s_ = gA + (size_t)(kt) * BK;                  \
    glds16(s_, ldsA + (bufi) * BUF_BYTES);                              \
    glds16(s_ + (size_t)128 * K_TOT, ldsA + (bufi) * BUF_BYTES + 8192); \
  } while (0)
#define STAGE_B(kt, bufi) do {                                          \
    const unsigned short* s_ = gB + (size_t)(kt) * BK;                  \
    glds16(s_, ldsB + (bufi) * BUF_BYTES);                              \
    glds16(s_ + (size_t)128 * K_TOT, ldsB + (bufi) * BUF_BYTES + 8192); \
  } while (0)

#define READ_AF(dst, bufi, mb) do {                                     \
    const char* p_ = smem + (bufi) * BUF_BYTES + base_a + (mb) * 1024;  \
    dst[0] = *(const bf16x8*)(p_);                                      \
    dst[1] = *(const bf16x8*)(p_ + 1024);                               \
    dst[2] = *(const bf16x8*)(p_ + 2048);                               \
    dst[3] = *(const bf16x8*)(p_ + 3072);                               \
  } while (0)
#define READ_BF(dst, bufi) do {                                         \
    const char* p_ = smem + (bufi) * BUF_BYTES + base_b;                \
    dst[0] = *(const bf16x8*)(p_);                                      \
    dst[1] = *(const bf16x8*)(p_ + 1024);                               \
    dst[2] = *(const bf16x8*)(p_ + 2048);                               \
    dst[3] = *(const bf16x8*)(p_ + 3072);                               \
  } while (0)

#define MFMA16(afs, bfs, mb) do {                                       \
    __builtin_amdgcn_s_setprio(1);                                      \
    _Pragma("unroll")                                                   \
    for (int m_ = 0; m_ < 4; ++m_)                                      \
      _Pragma("unroll")                                                 \
      for (int n_ = 0; n_ < 4; ++n_)                                    \
        acc[(mb) + m_][n_] = __builtin_amdgcn_mfma_f32_16x16x32_bf16(   \
            afs[m_], bfs[n_], acc[(mb) + m_][n_], 0, 0, 0);             \
    __builtin_amdgcn_s_setprio(0);                                      \
  } while (0)

#define VM(n) asm volatile("s_waitcnt vmcnt(" #n ")" ::: "memory")
#define BAR __builtin_amdgcn_s_barrier()

  // Phase A of tile tt (data in buf rb): read af m4-7 of tt, stage A(tt+3),
  // MFMA rows 0-3, then vmcnt(6) + barrier => tile tt+1 landed GLOBALLY.
#define PH_A(tt, rb, sb, bfc) do { \
    READ_AF(afB, rb, 4);           \
    STAGE_A((tt) + 3, sb);         \
    MFMA16(afA, bfc, 0);           \
    VM(6); BAR;                    \
  } while (0)
  // Phase B of tile tt: read-ahead af m0-3 + bf of tile tt+1 (safe: landed),
  // stage B(tt+3), MFMA rows 4-7, barrier.
#define PH_B(tt, rbn, sb, bfc, bfn) do { \
    READ_AF(afA, rbn, 0);                \
    READ_BF(bfn, rbn);                   \
    STAGE_B((tt) + 3, sb);               \
    MFMA16(afB, bfc, 4);                 \
    BAR;                                 \
  } while (0)

  // ---- prologue: stage tiles 0,1,2 (order pinned for vmcnt accounting)
  STAGE_A(0, 0); STAGE_B(0, 0);
  asm volatile("" ::: "memory");
  STAGE_A(1, 1); STAGE_B(1, 1);
  asm volatile("" ::: "memory");
  STAGE_A(2, 2); STAGE_B(2, 2);
  VM(8);  // tile 0 landed (own); barrier makes it global
  BAR;
  READ_AF(afA, 0, 0);
  READ_BF(bfE, 0);

  // ---- main loop: tiles 0..123, stages 3..126 (4-tile unroll, static bufs)
#pragma unroll 1
  for (int tt = 0; tt < NT - 4; tt += 4) {
    PH_A(tt + 0, 0, 3, bfE);
    PH_B(tt + 0, 1, 3, bfE, bfO);
    PH_A(tt + 1, 1, 0, bfO);
    PH_B(tt + 1, 2, 0, bfO, bfE);
    PH_A(tt + 2, 2, 1, bfE);
    PH_B(tt + 2, 3, 1, bfE, bfO);
    PH_A(tt + 3, 3, 2, bfO);
    PH_B(tt + 3, 0, 2, bfO, bfE);
  }

  // ---- tail: tiles 124..127, drain 6 -> 4 -> 0
  // tile 124 (buf0), stages tile 127 -> buf3
  READ_AF(afB, 0, 4); STAGE_A(127, 3); MFMA16(afA, bfE, 0); VM(6); BAR;
  READ_AF(afA, 1, 0); READ_BF(bfO, 1); STAGE_B(127, 3); MFMA16(afB, bfE, 4); BAR;
  // tile 125 (buf1): newest allowed = A(127)+B(127) = 4 => tile 126 landed
  READ_AF(afB, 1, 4); MFMA16(afA, bfO, 0); VM(4); BAR;
  READ_AF(afA, 2, 0); READ_BF(bfE, 2); MFMA16(afB, bfO, 4); BAR;
  // tile 126 (buf2): drain all => tile 127 landed
  READ_AF(afB, 2, 4); MFMA16(afA, bfE, 0); VM(0); BAR;
  READ_AF(afA, 3, 0); READ_BF(bfO, 3); MFMA16(afB, bfE, 4); BAR;
  // tile 127 (buf3)
  READ_AF(afB, 3, 4); MFMA16(afA, bfO, 0);
  MFMA16(afB, bfO, 4);

  // ---- epilogue: C/D layout col = lane&15, row = (lane>>4)*4 + q
  const int orow0 = bm0 + wr * 128 + (lane >> 4) * 4;
  const int ocol0 = bn0 + wc * 64 + ln;
  float bj[4];
#pragma unroll
  for (int n = 0; n < 4; ++n) bj[n] = bias[ocol0 + n * 16];
#pragma unroll
  for (int mi = 0; mi < 8; ++mi)
#pragma unroll
    for (int n = 0; n < 4; ++n)
#pragma unroll
      for (int q = 0; q < 4; ++q)
        out[(size_t)(orow0 + mi * 16 + q) * N_TOT + ocol0 + n * 16] =
            acc[mi][n][q] + bj[n];
}

extern "C" void kernel_launch(void* const* d_in, const int* in_sizes, int n_in,
                              void* d_out, int out_size, void* d_ws, size_t ws_size,
                              hipStream_t stream) {
  const float* x = (const float*)d_in[0];
  const int* widx = (const int*)d_in[1];
  const float* wsc = (const float*)d_in[2];
  const float* bias = (const float*)d_in[3];
  float* out = (float*)d_out;

  unsigned short* Abf = (unsigned short*)d_ws;                       // 64 MiB
  unsigned short* Wbf = (unsigned short*)((char*)d_ws + (size_t)M_TOT * K_TOT * 2);  // 32 MiB

  prepass_kernel<<<dim3(32768), dim3(256), 0, stream>>>(x, Abf, widx, wsc, Wbf);

  (void)hipFuncSetAttribute((const void*)gemm256,
                            hipFuncAttributeMaxDynamicSharedMemorySize, LDS_BYTES);
  gemm256<<<dim3((M_TOT / BM) * (N_TOT / BN)), dim3(GTHREADS), LDS_BYTES, stream>>>(
      Abf, Wbf, bias, out);
}